// Round 9
// baseline (178.242 us; speedup 1.0000x reference)
//
#include <hip/hip_runtime.h>

#define D_MODEL 1024
#define NUM_HEADS 16
#define D_HEAD 64
#define BATCH 2
#define SEQ 2048
#define MTOT (BATCH * SEQ) /* 4096 */
#define PLANE ((size_t)MTOT * D_MODEL)
#define QSCALE 0.1803368801f /* 0.125 * log2(e) : folds 1/sqrt(dh) and exp->exp2 */

typedef unsigned short us;
typedef __bf16 bf16x8 __attribute__((ext_vector_type(8)));
typedef float floatx4 __attribute__((ext_vector_type(4)));

// ---------- bf16 helpers ----------
__device__ __forceinline__ unsigned int f2bf(float f) {
  union { float f; unsigned int i; } v; v.f = f;
  unsigned int r = v.i + 0x7FFFu + ((v.i >> 16) & 1u); // RNE
  return r >> 16;
}
__device__ __forceinline__ unsigned int f2bf_tr(float f) {
  union { float f; unsigned int i; } v; v.f = f;
  return v.i >> 16;
}

// ---------- fused f32 -> bf16 conversion: x, Wq, Wk, Wv, Wo in one launch ----------
__global__ __launch_bounds__(256) void convert_all(const float* __restrict__ x,
                                                   const float* __restrict__ Wq,
                                                   const float* __restrict__ Wk,
                                                   const float* __restrict__ Wv,
                                                   const float* __restrict__ Wo,
                                                   us* __restrict__ xbf,
                                                   us* __restrict__ Wqkv,
                                                   us* __restrict__ Wobf) {
  const int i = blockIdx.x * 256 + threadIdx.x;  // float4 index
  const float* src;
  us* dst;
  if (i < (1 << 20)) {  // x: 4M elems = 1M float4
    src = x + (size_t)i * 4;
    dst = xbf + (size_t)i * 4;
  } else {
    const int j = i - (1 << 20);
    const int w = j >> 18;                // 0..3 (each W = 256K float4)
    const int o = j & ((1 << 18) - 1);
    if (w < 3) {
      const float* ws = (w == 0) ? Wq : (w == 1) ? Wk : Wv;
      src = ws + (size_t)o * 4;
      dst = Wqkv + (size_t)w * (D_MODEL * D_MODEL) + (size_t)o * 4;
    } else {
      src = Wo + (size_t)o * 4;
      dst = Wobf + (size_t)o * 4;
    }
  }
  float4 v = *(const float4*)src;
  uint2 pk;
  pk.x = f2bf(v.x) | (f2bf(v.y) << 16);
  pk.y = f2bf(v.z) | (f2bf(v.w) << 16);
  *(uint2*)dst = pk;
}

// ---------- MFMA GEMM: C(M,N) = A(M,K) * B(N,K)^T, bf16 inputs, fp32 acc ----------
// 2-PHASE PIPELINE (r5, verified) — r8's T2 swizzle REVERTED: it zeroed
// SQ_LDS_BANK_CONFLICT (3.1M->0) but cost +10us. The XOR'd global source
// permuted lanes within 64B lines; TA merging of the global_load_lds requests
// degraded, slowing the stage DMA, which IS the critical path of this 2-phase
// structure (conflicts were hidden; stage latency is not). m233 regime lesson.
// CMODE 1 (fused QKV, N=3072): plane0 -> Q*QSCALE, plane1 -> K, plane2 -> V
// written TRANSPOSED as Vt[b][h][d][s]. CMODE 2: f32 out.
template <int CMODE>
__global__ __launch_bounds__(256) void gemm_mfma(const us* __restrict__ A,
                                                 const us* __restrict__ B,
                                                 void* __restrict__ Cv,
                                                 int M, int N, int K) {
  __shared__ __bf16 As[2][128 * 32];
  __shared__ __bf16 Bs[2][128 * 32];
  const int tid = threadIdx.x;
  const int wid = tid >> 6;
  const int lane = tid & 63;
  const int bm = blockIdx.y * 128;
  const int bn = blockIdx.x * 128;
  const int wm = (wid & 1) * 64;
  const int wn = (wid >> 1) * 64;
  const int lr = lane & 15;
  const int quad = lane >> 4;

  floatx4 acc[4][4] = {};
  const int cb0 = wid * 128;

  auto stage = [&](int buf, int k0) {
#pragma unroll
    for (int p = 0; p < 2; ++p) {
      const int cb = cb0 + p * 64;
      const int c = cb + lane;
      const us* ga = A + (size_t)(bm + (c >> 2)) * K + (k0 + (c & 3) * 8);
      const us* gb = B + (size_t)(bn + (c >> 2)) * K + (k0 + (c & 3) * 8);
      __builtin_amdgcn_global_load_lds((const __attribute__((address_space(1))) void*)ga,
                                       (__attribute__((address_space(3))) void*)(&As[buf][cb * 8]),
                                       16, 0, 0);
      __builtin_amdgcn_global_load_lds((const __attribute__((address_space(1))) void*)gb,
                                       (__attribute__((address_space(3))) void*)(&Bs[buf][cb * 8]),
                                       16, 0, 0);
    }
  };

  stage(0, 0);
  __syncthreads();  // compiler inserts vmcnt(0): prologue tile landed

  int cur = 0;
  for (int k0 = 0; k0 < K; k0 += 32) {
    if (k0 + 32 < K) stage(cur ^ 1, k0 + 32);  // issue next-tile DMA first

    bf16x8 a[4], b[4];
#pragma unroll
    for (int i = 0; i < 4; ++i)
      a[i] = *(const bf16x8*)&As[cur][(wm + i * 16 + lr) * 32 + quad * 8];
#pragma unroll
    for (int j = 0; j < 4; ++j)
      b[j] = *(const bf16x8*)&Bs[cur][(wn + j * 16 + lr) * 32 + quad * 8];
#pragma unroll
    for (int i = 0; i < 4; ++i)
#pragma unroll
      for (int j = 0; j < 4; ++j)
        acc[i][j] = __builtin_amdgcn_mfma_f32_16x16x32_bf16(a[i], b[j], acc[i][j], 0, 0, 0);

    __syncthreads();  // vmcnt(0)+lgkmcnt(0): next buf ready, cur reads done
    cur ^= 1;
  }

  // C/D layout: col = lane&15, row = quad*4 + reg (verified r3/r4/r6)
#pragma unroll
  for (int i = 0; i < 4; ++i) {
#pragma unroll
    for (int j = 0; j < 4; ++j) {
      const int col = bn + wn + j * 16 + lr;
      if constexpr (CMODE == 1) {
        us* dst = (us*)Cv;
        const int plane = col >> 10;
        if (plane < 2) {
          const float s = (plane == 0) ? QSCALE : 1.0f;
#pragma unroll
          for (int r = 0; r < 4; ++r) {
            const int row = bm + wm + i * 16 + quad * 4 + r;
            dst[(size_t)plane * PLANE + (size_t)row * 1024 + (col & 1023)] =
                (us)f2bf(acc[i][j][r] * s);
          }
        } else {
          // V transposed: Vt[((b*16+h)*64+d)*2048 + s]; r-consecutive => s-consecutive
          const int d = col & 63;
          const int hh = (col >> 6) & 15;
          const int row0 = bm + wm + i * 16 + quad * 4;
          const int bb = row0 >> 11;
          const int ss = row0 & 2047;
          uint2 pk;
          pk.x = f2bf(acc[i][j][0]) | (f2bf(acc[i][j][1]) << 16);
          pk.y = f2bf(acc[i][j][2]) | (f2bf(acc[i][j][3]) << 16);
          *(uint2*)&dst[2 * PLANE + ((size_t)((bb * 16 + hh) * 64 + d)) * 2048 + ss] = pk;
        }
      } else {
#pragma unroll
        for (int r = 0; r < 4; ++r) {
          const int row = bm + wm + i * 16 + quad * 4 + r;
          ((float*)Cv)[(size_t)row * N + col] = acc[i][j][r];
        }
      }
    }
  }
}

// ---------- MFMA causal flash attention (transposed scores, LDS dbuf) ----------
// r5 VERIFIED STRUCTURE + P-BUFFER WRITE SWIZZLE (this round).
// Bank audit of the ASTR=72 layout: K/V frag reads, P frag reads, staging
// writes are all <=2-way (free). The P uint2 WRITES were 4-way: bank =
// 4*(lr&7) + 2*quad, ~2 (lr&7,quad) combos per bank x lr/lr+8 duplication
// (measured 4.2M conflict cycles ~= 6.8us of LDS-pipe time/CU on an LDS-pipe-
// bound kernel). Fix: XOR the key-offset with 32*(lr>>3) on P write AND the
// pa0/pa1 reads (wave-private buffer: both sides changed together, no staging
// interaction). Write bank becomes 4*(lr&7)+2*quad+16*(lr>>3) -> 2-way (free);
// reads stay 8-us aligned/contiguous, read bank group (lr+quad+-4h)%8 uniform.
// Epilogue stays linear (self-consistent, runs once).
// 8-WAVE BLOCKS (512 threads), 16 q-rows per wave, 128-row strips. LDS 54KB ->
// 2 blocks/CU. Double-buffered K/V staging, ONE barrier per tile; t+1 global
// loads issued before compute(t), ds_writes after. P-buffer wave-private.
// S^T = mfma(K,Q): key=quad*4+r, qrow=lr. O^T = mfma(Vt,P), l^T = mfma(ones,P).
// Block bx / bx+256 get complementary strips (s0, 15-s0).
#define ASTR 72 /* us per LDS row */

__global__ __launch_bounds__(512, 2) void attn_mfma(const us* __restrict__ Qb,
                                                    const us* __restrict__ Kb,
                                                    const us* __restrict__ Vtg,
                                                    us* __restrict__ Ob) {
  const int bx = blockIdx.x;
  const int b = bx >> 8;
  const int idx = bx & 255;
  const int h = idx >> 4;
  const int s0 = idx & 15;
  const int strip = b ? (15 - s0) : s0;  // pair (n, n+256): strips sum to 15
  const int q0 = strip * 128;
  const int ntiles = 2 * strip + 2;
  const int tid = threadIdx.x;
  const int w = tid >> 6;       // 0..7
  const int lane = tid & 63;
  const int lr = lane & 15;
  const int quad = lane >> 4;
  const int xh = (lr & 8) * 4;  // 32*(lr>>3): P-buffer bank swizzle

  __shared__ us Ks[2][64 * ASTR];   // K tile [key][dim], double-buffered
  __shared__ us Vs[2][64 * ASTR];   // V tile [dim][key] (pre-transposed)
  __shared__ us Ps[8 * 16 * ASTR];  // per-wave P [qrow][key^swz]

  const us* kbase = Kb + (size_t)(b * SEQ) * D_MODEL + h * D_HEAD;
  const us* vbase = Vtg + (size_t)((b * 16 + h) * 64) * 2048;
  us* const pg = &Ps[w * 16 * ASTR];

  const int grow = q0 + w * 16;  // this wave's first qrow
  // Q frags (MFMA B-operand: n=qrow=lr, k=quad*8+j)
  const us* qp = Qb + (size_t)(b * SEQ + grow + lr) * D_MODEL + h * D_HEAD;
  const bf16x8 qa0 = *(const bf16x8*)(qp + quad * 8);
  const bf16x8 qa1 = *(const bf16x8*)(qp + 32 + quad * 8);

  floatx4 oacc[4] = {};  // [nt]: O^T — rows dim=nt*16+quad*4+r, col qrow=lr
  floatx4 lacc = {};     // l^T — col qrow=lr (rows identical)
  bf16x8 ones;
#pragma unroll
  for (int i = 0; i < 8; ++i) ones[i] = (__bf16)1.0f;

  // staging geometry: 512 threads cover one 64x64 bf16 tile (64 rows x 8 chunks)
  const int srow = tid >> 3;   // 0..63
  const int schunk = tid & 7;  // 0..7

  // prologue: tile 0 -> regs -> LDS buf 0 -> barrier
  uint4 kreg, vreg;
  kreg = *(const uint4*)(kbase + (size_t)srow * D_MODEL + schunk * 8);
  vreg = *(const uint4*)(vbase + (size_t)srow * 2048 + schunk * 8);
  *(uint4*)&Ks[0][srow * ASTR + schunk * 8] = kreg;
  *(uint4*)&Vs[0][srow * ASTR + schunk * 8] = vreg;
  __syncthreads();

  for (int t = 0; t < ntiles; ++t) {
    const int k0 = t * 64;
    const int cur = t & 1;
    const bool more = (t + 1 < ntiles);

    // issue t+1 global loads first: latency hidden behind compute(t)
    if (more) {
      const int kn = k0 + 64;
      kreg = *(const uint4*)(kbase + (size_t)(kn + srow) * D_MODEL + schunk * 8);
      vreg = *(const uint4*)(vbase + (size_t)srow * 2048 + kn + schunk * 8);
    }

    // ---- S^T = K Q^T per 16-key block; exp2; b64 P-writes (swizzled) ----
#pragma unroll
    for (int jt = 0; jt < 4; ++jt) {
      const bf16x8 kb0 = *(const bf16x8*)&Ks[cur][(jt * 16 + lr) * ASTR + quad * 8];
      const bf16x8 kb1 = *(const bf16x8*)&Ks[cur][(jt * 16 + lr) * ASTR + 32 + quad * 8];
      floatx4 s = {};
      s = __builtin_amdgcn_mfma_f32_16x16x32_bf16(kb0, qa0, s, 0, 0, 0);
      s = __builtin_amdgcn_mfma_f32_16x16x32_bf16(kb1, qa1, s, 0, 0, 0);
      const int kb = k0 + jt * 16 + quad * 4;  // key = kb + r
      const bool needMask = (k0 + jt * 16 + 15 > grow);
      float p[4];
#pragma unroll
      for (int r = 0; r < 4; ++r) {
        float e = __builtin_amdgcn_exp2f(s[r]);
        if (needMask && (kb + r > grow + lr)) e = 0.f;
        p[r] = e;
      }
      uint2 pk;
      pk.x = f2bf_tr(p[0]) | (f2bf_tr(p[1]) << 16);
      pk.y = f2bf_tr(p[2]) | (f2bf_tr(p[3]) << 16);
      *(uint2*)&pg[lr * ASTR + ((jt * 16 + quad * 4) ^ xh)] = pk;
    }

    // ---- P B-frags (swizzled reads); l^T and O^T accumulate ----
    const bf16x8 pa0 = *(const bf16x8*)&pg[lr * ASTR + ((quad * 8) ^ xh)];
    const bf16x8 pa1 = *(const bf16x8*)&pg[lr * ASTR + ((32 + quad * 8) ^ xh)];
    lacc = __builtin_amdgcn_mfma_f32_16x16x32_bf16(ones, pa0, lacc, 0, 0, 0);
    lacc = __builtin_amdgcn_mfma_f32_16x16x32_bf16(ones, pa1, lacc, 0, 0, 0);
#pragma unroll
    for (int nt = 0; nt < 4; ++nt) {
      const bf16x8 vb0 = *(const bf16x8*)&Vs[cur][(nt * 16 + lr) * ASTR + quad * 8];
      const bf16x8 vb1 = *(const bf16x8*)&Vs[cur][(nt * 16 + lr) * ASTR + 32 + quad * 8];
      oacc[nt] = __builtin_amdgcn_mfma_f32_16x16x32_bf16(vb0, pa0, oacc[nt], 0, 0, 0);
      oacc[nt] = __builtin_amdgcn_mfma_f32_16x16x32_bf16(vb1, pa1, oacc[nt], 0, 0, 0);
    }

    // ---- write t+1 into the other buffer; single barrier ----
    if (more) {
      const int nxt = cur ^ 1;
      *(uint4*)&Ks[nxt][srow * ASTR + schunk * 8] = kreg;
      *(uint4*)&Vs[nxt][srow * ASTR + schunk * 8] = vreg;
    }
    __syncthreads();
  }

  // ---- epilogue: O^T/l -> pg as [qrow][dim] (linear, self-consistent) ----
  const float inv = 1.f / lacc[0];  // all 4 regs equal (l^T rows identical)
#pragma unroll
  for (int nt = 0; nt < 4; ++nt) {
    uint2 pk;
    pk.x = f2bf_tr(oacc[nt][0] * inv) | (f2bf_tr(oacc[nt][1] * inv) << 16);
    pk.y = f2bf_tr(oacc[nt][2] * inv) | (f2bf_tr(oacc[nt][3] * inv) << 16);
    *(uint2*)&pg[lr * ASTR + nt * 16 + quad * 4] = pk;
  }
#pragma unroll
  for (int p = 0; p < 2; ++p) {
    const int c = lane + 64 * p;  // row = c>>3 (0..15), chunk = c&7
    *(uint4*)(Ob + (size_t)(b * SEQ + grow + (c >> 3)) * D_MODEL + h * D_HEAD + (c & 7) * 8) =
        *(const uint4*)&pg[(c >> 3) * ASTR + (c & 7) * 8];
  }
}

extern "C" void kernel_launch(void* const* d_in, const int* in_sizes, int n_in,
                              void* d_out, int out_size, void* d_ws, size_t ws_size,
                              hipStream_t stream) {
  const float* x  = (const float*)d_in[0];
  const float* Wq = (const float*)d_in[1];
  const float* Wk = (const float*)d_in[2];
  const float* Wv = (const float*)d_in[3];
  const float* Wo = (const float*)d_in[4];

  // ws: [x_bf | Qb | Kb | Vt | Wobf]; Ab aliases x_bf (x dead after QKV GEMM).
  us* xbf = (us*)d_ws;
  us* Qb  = xbf + PLANE;
  us* Kb  = xbf + 2 * PLANE;
  us* Vt  = xbf + 3 * PLANE;   // Vt[b][h][d][s], 8 MB
  us* Wobf = xbf + 4 * PLANE;  // 2 MB, lives at d_ws+32MB
  us* Ab  = xbf;
  // d_out (16 MB f32) doubles as scratch for fused Wqkv_bf (6 MB) until final GEMM.
  us* Wqkv = (us*)d_out;
  float* out = (float*)d_out;

  convert_all<<<8192, 256, 0, stream>>>(x, Wq, Wk, Wv, Wo, xbf, Wqkv, Wobf);

  gemm_mfma<1><<<dim3(3072 / 128, MTOT / 128), 256, 0, stream>>>(xbf, Wqkv, Qb, MTOT, 3072, D_MODEL);

  attn_mfma<<<512, 512, 0, stream>>>(Qb, Kb, Vt, Ab);

  gemm_mfma<2><<<dim3(D_MODEL / 128, MTOT / 128), 256, 0, stream>>>(Ab, Wobf, out, MTOT, D_MODEL, D_MODEL);
}

// Round 10
// 174.675 us; speedup vs baseline: 1.0204x; 1.0204x over previous
//
#include <hip/hip_runtime.h>

#define D_MODEL 1024
#define NUM_HEADS 16
#define D_HEAD 64
#define BATCH 2
#define SEQ 2048
#define MTOT (BATCH * SEQ) /* 4096 */
#define PLANE ((size_t)MTOT * D_MODEL)
#define QSCALE 0.1803368801f /* 0.125 * log2(e) : folds 1/sqrt(dh) and exp->exp2 */

typedef unsigned short us;
typedef __bf16 bf16x8 __attribute__((ext_vector_type(8)));
typedef float floatx4 __attribute__((ext_vector_type(4)));

// ---------- bf16 helpers ----------
__device__ __forceinline__ unsigned int f2bf(float f) {
  union { float f; unsigned int i; } v; v.f = f;
  unsigned int r = v.i + 0x7FFFu + ((v.i >> 16) & 1u); // RNE
  return r >> 16;
}
__device__ __forceinline__ unsigned int f2bf_tr(float f) {
  union { float f; unsigned int i; } v; v.f = f;
  return v.i >> 16;
}

// ---------- fused f32 -> bf16 conversion: x, Wq, Wk, Wv, Wo in one launch ----------
__global__ __launch_bounds__(256) void convert_all(const float* __restrict__ x,
                                                   const float* __restrict__ Wq,
                                                   const float* __restrict__ Wk,
                                                   const float* __restrict__ Wv,
                                                   const float* __restrict__ Wo,
                                                   us* __restrict__ xbf,
                                                   us* __restrict__ Wqkv,
                                                   us* __restrict__ Wobf) {
  const int i = blockIdx.x * 256 + threadIdx.x;  // float4 index
  const float* src;
  us* dst;
  if (i < (1 << 20)) {  // x: 4M elems = 1M float4
    src = x + (size_t)i * 4;
    dst = xbf + (size_t)i * 4;
  } else {
    const int j = i - (1 << 20);
    const int w = j >> 18;                // 0..3 (each W = 256K float4)
    const int o = j & ((1 << 18) - 1);
    if (w < 3) {
      const float* ws = (w == 0) ? Wq : (w == 1) ? Wk : Wv;
      src = ws + (size_t)o * 4;
      dst = Wqkv + (size_t)w * (D_MODEL * D_MODEL) + (size_t)o * 4;
    } else {
      src = Wo + (size_t)o * 4;
      dst = Wobf + (size_t)o * 4;
    }
  }
  float4 v = *(const float4*)src;
  uint2 pk;
  pk.x = f2bf(v.x) | (f2bf(v.y) << 16);
  pk.y = f2bf(v.z) | (f2bf(v.w) << 16);
  *(uint2*)dst = pk;
}

// ---------- MFMA GEMM: C(M,N) = A(M,K) * B(N,K)^T, bf16 inputs, fp32 acc ----------
// 2-PHASE PIPELINE (r5, verified): double-buffered global_load_lds staging;
// t+1 stage ISSUED before compute(t); ONE barrier per K-step. r8's source-side
// swizzle stays reverted (zeroed conflicts but broke TA request merging: +10us;
// conflicts are hidden in this regime, stage latency is not).
// CMODE 1 (fused QKV, N=3072): plane0 -> Q*QSCALE, plane1 -> K, plane2 -> V
// written TRANSPOSED as Vt[b][h][d][s]. CMODE 2: f32 out (unused this round).
template <int CMODE>
__global__ __launch_bounds__(256) void gemm_mfma(const us* __restrict__ A,
                                                 const us* __restrict__ B,
                                                 void* __restrict__ Cv,
                                                 int M, int N, int K) {
  __shared__ __bf16 As[2][128 * 32];
  __shared__ __bf16 Bs[2][128 * 32];
  const int tid = threadIdx.x;
  const int wid = tid >> 6;
  const int lane = tid & 63;
  const int bm = blockIdx.y * 128;
  const int bn = blockIdx.x * 128;
  const int wm = (wid & 1) * 64;
  const int wn = (wid >> 1) * 64;
  const int lr = lane & 15;
  const int quad = lane >> 4;

  floatx4 acc[4][4] = {};
  const int cb0 = wid * 128;

  auto stage = [&](int buf, int k0) {
#pragma unroll
    for (int p = 0; p < 2; ++p) {
      const int cb = cb0 + p * 64;
      const int c = cb + lane;
      const us* ga = A + (size_t)(bm + (c >> 2)) * K + (k0 + (c & 3) * 8);
      const us* gb = B + (size_t)(bn + (c >> 2)) * K + (k0 + (c & 3) * 8);
      __builtin_amdgcn_global_load_lds((const __attribute__((address_space(1))) void*)ga,
                                       (__attribute__((address_space(3))) void*)(&As[buf][cb * 8]),
                                       16, 0, 0);
      __builtin_amdgcn_global_load_lds((const __attribute__((address_space(1))) void*)gb,
                                       (__attribute__((address_space(3))) void*)(&Bs[buf][cb * 8]),
                                       16, 0, 0);
    }
  };

  stage(0, 0);
  __syncthreads();  // compiler inserts vmcnt(0): prologue tile landed

  int cur = 0;
  for (int k0 = 0; k0 < K; k0 += 32) {
    if (k0 + 32 < K) stage(cur ^ 1, k0 + 32);  // issue next-tile DMA first

    bf16x8 a[4], b[4];
#pragma unroll
    for (int i = 0; i < 4; ++i)
      a[i] = *(const bf16x8*)&As[cur][(wm + i * 16 + lr) * 32 + quad * 8];
#pragma unroll
    for (int j = 0; j < 4; ++j)
      b[j] = *(const bf16x8*)&Bs[cur][(wn + j * 16 + lr) * 32 + quad * 8];
#pragma unroll
    for (int i = 0; i < 4; ++i)
#pragma unroll
      for (int j = 0; j < 4; ++j)
        acc[i][j] = __builtin_amdgcn_mfma_f32_16x16x32_bf16(a[i], b[j], acc[i][j], 0, 0, 0);

    __syncthreads();  // vmcnt(0)+lgkmcnt(0): next buf ready, cur reads done
    cur ^= 1;
  }

  // C/D layout: col = lane&15, row = quad*4 + reg (verified r3/r4/r6)
#pragma unroll
  for (int i = 0; i < 4; ++i) {
#pragma unroll
    for (int j = 0; j < 4; ++j) {
      const int col = bn + wn + j * 16 + lr;
      if constexpr (CMODE == 1) {
        us* dst = (us*)Cv;
        const int plane = col >> 10;
        if (plane < 2) {
          const float s = (plane == 0) ? QSCALE : 1.0f;
#pragma unroll
          for (int r = 0; r < 4; ++r) {
            const int row = bm + wm + i * 16 + quad * 4 + r;
            dst[(size_t)plane * PLANE + (size_t)row * 1024 + (col & 1023)] =
                (us)f2bf(acc[i][j][r] * s);
          }
        } else {
          // V transposed: Vt[((b*16+h)*64+d)*2048 + s]; r-consecutive => s-consecutive
          const int d = col & 63;
          const int hh = (col >> 6) & 15;
          const int row0 = bm + wm + i * 16 + quad * 4;
          const int bb = row0 >> 11;
          const int ss = row0 & 2047;
          uint2 pk;
          pk.x = f2bf(acc[i][j][0]) | (f2bf(acc[i][j][1]) << 16);
          pk.y = f2bf(acc[i][j][2]) | (f2bf(acc[i][j][3]) << 16);
          *(uint2*)&dst[2 * PLANE + ((size_t)((bb * 16 + hh) * 64 + d)) * 2048 + ss] = pk;
        }
      } else {
#pragma unroll
        for (int r = 0; r < 4; ++r) {
          const int row = bm + wm + i * 16 + quad * 4 + r;
          ((float*)Cv)[(size_t)row * N + col] = acc[i][j][r];
        }
      }
    }
  }
}

// ---------- MFMA GEMM, BN=64 tile (output projection): C f32 ----------
// gemm2's old grid (1024/128, 4096/128) = 256 blocks = 1 block/CU: the solo-
// block regime r2 measured at ~0.6x throughput (2-phase stage latency exposed,
// nothing co-resident to interleave). BN=64 -> grid (16,32)=512 blocks =
// 2 blocks/CU (24KB LDS each), doubling TLP for the same total work.
// Per wave: 32 rows x 64 cols, acc[2][4]. Staging per buf: A 8KB (2 issues/
// wave), B 4KB (1 issue/wave). Same verified frag/epilogue mapping (wn=0).
__global__ __launch_bounds__(256) void gemm_n64(const us* __restrict__ A,
                                                const us* __restrict__ B,
                                                float* __restrict__ C,
                                                int M, int N, int K) {
  __shared__ __bf16 As[2][128 * 32];
  __shared__ __bf16 Bs[2][64 * 32];
  const int tid = threadIdx.x;
  const int wid = tid >> 6;
  const int lane = tid & 63;
  const int bm = blockIdx.y * 128;
  const int bn = blockIdx.x * 64;
  const int wm = wid * 32;
  const int lr = lane & 15;
  const int quad = lane >> 4;

  floatx4 acc[2][4] = {};

  auto stage = [&](int buf, int k0) {
#pragma unroll
    for (int p = 0; p < 2; ++p) {
      const int cb = wid * 128 + p * 64;
      const int c = cb + lane;
      const us* ga = A + (size_t)(bm + (c >> 2)) * K + (k0 + (c & 3) * 8);
      __builtin_amdgcn_global_load_lds((const __attribute__((address_space(1))) void*)ga,
                                       (__attribute__((address_space(3))) void*)(&As[buf][cb * 8]),
                                       16, 0, 0);
    }
    const int cb2 = wid * 64;
    const int c2 = cb2 + lane;
    const us* gb = B + (size_t)(bn + (c2 >> 2)) * K + (k0 + (c2 & 3) * 8);
    __builtin_amdgcn_global_load_lds((const __attribute__((address_space(1))) void*)gb,
                                     (__attribute__((address_space(3))) void*)(&Bs[buf][cb2 * 8]),
                                     16, 0, 0);
  };

  stage(0, 0);
  __syncthreads();

  int cur = 0;
  for (int k0 = 0; k0 < K; k0 += 32) {
    if (k0 + 32 < K) stage(cur ^ 1, k0 + 32);  // issue next-tile DMA first

    bf16x8 a[2], b[4];
#pragma unroll
    for (int i = 0; i < 2; ++i)
      a[i] = *(const bf16x8*)&As[cur][(wm + i * 16 + lr) * 32 + quad * 8];
#pragma unroll
    for (int j = 0; j < 4; ++j)
      b[j] = *(const bf16x8*)&Bs[cur][(j * 16 + lr) * 32 + quad * 8];
#pragma unroll
    for (int i = 0; i < 2; ++i)
#pragma unroll
      for (int j = 0; j < 4; ++j)
        acc[i][j] = __builtin_amdgcn_mfma_f32_16x16x32_bf16(a[i], b[j], acc[i][j], 0, 0, 0);

    __syncthreads();
    cur ^= 1;
  }

  // C/D layout: col = lane&15, row = quad*4 + reg (verified r3/r4/r6)
#pragma unroll
  for (int i = 0; i < 2; ++i) {
#pragma unroll
    for (int j = 0; j < 4; ++j) {
      const int col = bn + j * 16 + lr;
#pragma unroll
      for (int r = 0; r < 4; ++r) {
        const int row = bm + wm + i * 16 + quad * 4 + r;
        C[(size_t)row * N + col] = acc[i][j][r];
      }
    }
  }
}

// ---------- MFMA causal flash attention (transposed scores, LDS dbuf) ----------
// r5 VERIFIED VERSION, exact. (r9's P-write swizzle reverted: predicted -4us,
// measured +2.5 total -> conflicts are hidden under staging/barrier slack, the
// same regime lesson as gemm's r8 swizzle. Rule #13: unverified micro-deltas
// don't ship.) 8-WAVE BLOCKS (512 threads), 16 q-rows per wave, 128-row
// strips. LDS 54KB -> 2 blocks/CU. Double-buffered K/V staging (1 uint4 K +
// 1 uint4 V per thread), ONE barrier per tile; t+1 global loads issued before
// compute(t), ds_writes after. P-buffer wave-private. S^T = mfma(K,Q):
// key=quad*4+r, qrow=lr => 4 P values/lane LDS-consecutive => b64 writes.
// O^T = mfma(Vt,P), l^T = mfma(ones,P). Blocks bx / bx+256 get complementary
// strips (s0, 15-s0): per-CU pair workload is a constant 34 tiles.
#define ASTR 72 /* us per LDS row */

__global__ __launch_bounds__(512, 2) void attn_mfma(const us* __restrict__ Qb,
                                                    const us* __restrict__ Kb,
                                                    const us* __restrict__ Vtg,
                                                    us* __restrict__ Ob) {
  const int bx = blockIdx.x;
  const int b = bx >> 8;
  const int idx = bx & 255;
  const int h = idx >> 4;
  const int s0 = idx & 15;
  const int strip = b ? (15 - s0) : s0;  // pair (n, n+256): strips sum to 15
  const int q0 = strip * 128;
  const int ntiles = 2 * strip + 2;
  const int tid = threadIdx.x;
  const int w = tid >> 6;       // 0..7
  const int lane = tid & 63;
  const int lr = lane & 15;
  const int quad = lane >> 4;

  __shared__ us Ks[2][64 * ASTR];   // K tile [key][dim], double-buffered
  __shared__ us Vs[2][64 * ASTR];   // V tile [dim][key] (pre-transposed)
  __shared__ us Ps[8 * 16 * ASTR];  // per-wave P [qrow][key]

  const us* kbase = Kb + (size_t)(b * SEQ) * D_MODEL + h * D_HEAD;
  const us* vbase = Vtg + (size_t)((b * 16 + h) * 64) * 2048;
  us* const pg = &Ps[w * 16 * ASTR];

  const int grow = q0 + w * 16;  // this wave's first qrow
  // Q frags (MFMA B-operand: n=qrow=lr, k=quad*8+j)
  const us* qp = Qb + (size_t)(b * SEQ + grow + lr) * D_MODEL + h * D_HEAD;
  const bf16x8 qa0 = *(const bf16x8*)(qp + quad * 8);
  const bf16x8 qa1 = *(const bf16x8*)(qp + 32 + quad * 8);

  floatx4 oacc[4] = {};  // [nt]: O^T — rows dim=nt*16+quad*4+r, col qrow=lr
  floatx4 lacc = {};     // l^T — col qrow=lr (rows identical)
  bf16x8 ones;
#pragma unroll
  for (int i = 0; i < 8; ++i) ones[i] = (__bf16)1.0f;

  // staging geometry: 512 threads cover one 64x64 bf16 tile (64 rows x 8 chunks)
  const int srow = tid >> 3;   // 0..63
  const int schunk = tid & 7;  // 0..7

  // prologue: tile 0 -> regs -> LDS buf 0 -> barrier
  uint4 kreg, vreg;
  kreg = *(const uint4*)(kbase + (size_t)srow * D_MODEL + schunk * 8);
  vreg = *(const uint4*)(vbase + (size_t)srow * 2048 + schunk * 8);
  *(uint4*)&Ks[0][srow * ASTR + schunk * 8] = kreg;
  *(uint4*)&Vs[0][srow * ASTR + schunk * 8] = vreg;
  __syncthreads();

  for (int t = 0; t < ntiles; ++t) {
    const int k0 = t * 64;
    const int cur = t & 1;
    const bool more = (t + 1 < ntiles);

    // issue t+1 global loads first: latency hidden behind compute(t)
    if (more) {
      const int kn = k0 + 64;
      kreg = *(const uint4*)(kbase + (size_t)(kn + srow) * D_MODEL + schunk * 8);
      vreg = *(const uint4*)(vbase + (size_t)srow * 2048 + kn + schunk * 8);
    }

    // ---- S^T = K Q^T per 16-key block; exp2; b64 P-writes ----
#pragma unroll
    for (int jt = 0; jt < 4; ++jt) {
      const bf16x8 kb0 = *(const bf16x8*)&Ks[cur][(jt * 16 + lr) * ASTR + quad * 8];
      const bf16x8 kb1 = *(const bf16x8*)&Ks[cur][(jt * 16 + lr) * ASTR + 32 + quad * 8];
      floatx4 s = {};
      s = __builtin_amdgcn_mfma_f32_16x16x32_bf16(kb0, qa0, s, 0, 0, 0);
      s = __builtin_amdgcn_mfma_f32_16x16x32_bf16(kb1, qa1, s, 0, 0, 0);
      const int kb = k0 + jt * 16 + quad * 4;  // key = kb + r
      const bool needMask = (k0 + jt * 16 + 15 > grow);
      float p[4];
#pragma unroll
      for (int r = 0; r < 4; ++r) {
        float e = __builtin_amdgcn_exp2f(s[r]);
        if (needMask && (kb + r > grow + lr)) e = 0.f;
        p[r] = e;
      }
      uint2 pk;
      pk.x = f2bf_tr(p[0]) | (f2bf_tr(p[1]) << 16);
      pk.y = f2bf_tr(p[2]) | (f2bf_tr(p[3]) << 16);
      *(uint2*)&pg[lr * ASTR + jt * 16 + quad * 4] = pk;
    }

    // ---- P B-frags; l^T and O^T accumulate ----
    const bf16x8 pa0 = *(const bf16x8*)&pg[lr * ASTR + quad * 8];
    const bf16x8 pa1 = *(const bf16x8*)&pg[lr * ASTR + 32 + quad * 8];
    lacc = __builtin_amdgcn_mfma_f32_16x16x32_bf16(ones, pa0, lacc, 0, 0, 0);
    lacc = __builtin_amdgcn_mfma_f32_16x16x32_bf16(ones, pa1, lacc, 0, 0, 0);
#pragma unroll
    for (int nt = 0; nt < 4; ++nt) {
      const bf16x8 vb0 = *(const bf16x8*)&Vs[cur][(nt * 16 + lr) * ASTR + quad * 8];
      const bf16x8 vb1 = *(const bf16x8*)&Vs[cur][(nt * 16 + lr) * ASTR + 32 + quad * 8];
      oacc[nt] = __builtin_amdgcn_mfma_f32_16x16x32_bf16(vb0, pa0, oacc[nt], 0, 0, 0);
      oacc[nt] = __builtin_amdgcn_mfma_f32_16x16x32_bf16(vb1, pa1, oacc[nt], 0, 0, 0);
    }

    // ---- write t+1 into the other buffer; single barrier ----
    if (more) {
      const int nxt = cur ^ 1;
      *(uint4*)&Ks[nxt][srow * ASTR + schunk * 8] = kreg;
      *(uint4*)&Vs[nxt][srow * ASTR + schunk * 8] = vreg;
    }
    __syncthreads();
  }

  // ---- epilogue: O^T/l -> pg as [qrow][dim] (b64 writes) -> 16B stores ----
  const float inv = 1.f / lacc[0];  // all 4 regs equal (l^T rows identical)
#pragma unroll
  for (int nt = 0; nt < 4; ++nt) {
    uint2 pk;
    pk.x = f2bf_tr(oacc[nt][0] * inv) | (f2bf_tr(oacc[nt][1] * inv) << 16);
    pk.y = f2bf_tr(oacc[nt][2] * inv) | (f2bf_tr(oacc[nt][3] * inv) << 16);
    *(uint2*)&pg[lr * ASTR + nt * 16 + quad * 4] = pk;
  }
#pragma unroll
  for (int p = 0; p < 2; ++p) {
    const int c = lane + 64 * p;  // row = c>>3 (0..15), chunk = c&7
    *(uint4*)(Ob + (size_t)(b * SEQ + grow + (c >> 3)) * D_MODEL + h * D_HEAD + (c & 7) * 8) =
        *(const uint4*)&pg[(c >> 3) * ASTR + (c & 7) * 8];
  }
}

extern "C" void kernel_launch(void* const* d_in, const int* in_sizes, int n_in,
                              void* d_out, int out_size, void* d_ws, size_t ws_size,
                              hipStream_t stream) {
  const float* x  = (const float*)d_in[0];
  const float* Wq = (const float*)d_in[1];
  const float* Wk = (const float*)d_in[2];
  const float* Wv = (const float*)d_in[3];
  const float* Wo = (const float*)d_in[4];

  // ws: [x_bf | Qb | Kb | Vt | Wobf]; Ab aliases x_bf (x dead after QKV GEMM).
  us* xbf = (us*)d_ws;
  us* Qb  = xbf + PLANE;
  us* Kb  = xbf + 2 * PLANE;
  us* Vt  = xbf + 3 * PLANE;   // Vt[b][h][d][s], 8 MB
  us* Wobf = xbf + 4 * PLANE;  // 2 MB, lives at d_ws+32MB
  us* Ab  = xbf;
  // d_out (16 MB f32) doubles as scratch for fused Wqkv_bf (6 MB) until final GEMM.
  us* Wqkv = (us*)d_out;
  float* out = (float*)d_out;

  convert_all<<<8192, 256, 0, stream>>>(x, Wq, Wk, Wv, Wo, xbf, Wqkv, Wobf);

  gemm_mfma<1><<<dim3(3072 / 128, MTOT / 128), 256, 0, stream>>>(xbf, Wqkv, Qb, MTOT, 3072, D_MODEL);

  attn_mfma<<<512, 512, 0, stream>>>(Qb, Kb, Vt, Ab);

  gemm_n64<<<dim3(D_MODEL / 64, MTOT / 128), 256, 0, stream>>>(Ab, Wobf, out, MTOT, D_MODEL, D_MODEL);
}